// Round 1
// 2910.145 us; speedup vs baseline: 3.9820x; 3.9820x over previous
//
#include <hip/hip_runtime.h>
#include <stdint.h>

#define N_NODES 20000
#define N_EDGES 200000
#define HSIZE   (1u << 19)
#define HMASK   (HSIZE - 1u)
#define INV_TEMP 0.17677669529663689f  // 1/sqrt(32)

typedef __bf16 bf16x8 __attribute__((ext_vector_type(8)));
typedef float  f32x4  __attribute__((ext_vector_type(4)));

__device__ __forceinline__ float bf2f(unsigned short u) {
  union { unsigned int i; float f; } x; x.i = ((unsigned int)u) << 16; return x.f;
}
__device__ __forceinline__ unsigned short f2bf(float f) {
  unsigned int u = __float_as_uint(f);
  u += 0x7fffu + ((u >> 16) & 1u);
  return (unsigned short)(u >> 16);
}

typedef __attribute__((address_space(1))) unsigned int* gas_t;
typedef __attribute__((address_space(3))) unsigned int* las_t;
__device__ __forceinline__ void load_g2l16(const void* g, void* l) {
  __builtin_amdgcn_global_load_lds((gas_t)g, (las_t)l, 16, 0, 0);
}

// ---------------- elementwise cast ----------------
__global__ void cast_bf16_k(const float* __restrict__ s, unsigned short* __restrict__ d, int n) {
  int i = (blockIdx.x * 256 + threadIdx.x) * 4;
  if (i < n) {
    float4 v = *(const float4*)(s + i);
    ushort4 o; o.x = f2bf(v.x); o.y = f2bf(v.y); o.z = f2bf(v.z); o.w = f2bf(v.w);
    *(ushort4*)(d + i) = o;
  }
}

// ---------------- reverse-edge hash ----------------
__device__ __forceinline__ unsigned int hslot(unsigned int k) {
  k *= 0x9E3779B1u; k ^= k >> 16; return k & HMASK;
}
__global__ void hash_insert_k(const int* __restrict__ ei, unsigned long long* __restrict__ tab) {
  int e = blockIdx.x * 256 + threadIdx.x;
  if (e >= N_EDGES) return;
  unsigned int r = (unsigned int)ei[e], c = (unsigned int)ei[N_EDGES + e];
  unsigned int key = r * (unsigned int)N_NODES + c;
  unsigned long long val = (((unsigned long long)key) << 32) | (unsigned int)e;
  unsigned int h = hslot(key);
  for (unsigned int p = 0; p < HSIZE; ++p) {
    unsigned long long old = atomicCAS(&tab[h], ~0ull, val);
    if (old == ~0ull || (unsigned int)(old >> 32) == key) return;
    h = (h + 1u) & HMASK;
  }
}
__global__ void hash_lookup_k(const int* __restrict__ ei, const unsigned long long* __restrict__ tab,
                              int* __restrict__ rev) {
  int e = blockIdx.x * 256 + threadIdx.x;
  if (e >= N_EDGES) return;
  unsigned int r = (unsigned int)ei[e], c = (unsigned int)ei[N_EDGES + e];
  unsigned int key = c * (unsigned int)N_NODES + r;
  unsigned int h = hslot(key);
  int res = -1;
  for (unsigned int p = 0; p < HSIZE; ++p) {
    unsigned long long v = tab[h];
    if (v == ~0ull) break;
    if ((unsigned int)(v >> 32) == key) { res = (int)(unsigned int)(v & 0xffffffffull); break; }
    h = (h + 1u) & HMASK;
  }
  rev[e] = res;
}

// ---------------- CSR by row (for zero-atomic segment ops) ----------------
__global__ void degree_k(const int* __restrict__ ei, int* __restrict__ ocnt, int* __restrict__ icnt) {
  int e = blockIdx.x * 256 + threadIdx.x;
  if (e < N_EDGES) { atomicAdd(&ocnt[ei[e]], 1); atomicAdd(&icnt[ei[N_EDGES + e]], 1); }
}
// exclusive scan of cnt[0..n) -> start[0..n], single block of 256
__global__ void scan_k(const int* __restrict__ cnt, int* __restrict__ start, int n) {
  __shared__ int part[256];
  int t = threadIdx.x;
  int chunk = (n + 255) / 256;
  int a = t * chunk, b = a + chunk; if (b > n) b = n; if (a > n) a = n;
  int s = 0;
  for (int i = a; i < b; ++i) s += cnt[i];
  part[t] = s;
  __syncthreads();
  for (int off = 1; off < 256; off <<= 1) {
    int v = (t >= off) ? part[t - off] : 0;
    __syncthreads();
    part[t] += v;
    __syncthreads();
  }
  int excl = (t == 0) ? 0 : part[t - 1];
  for (int i = a; i < b; ++i) { start[i] = excl; excl += cnt[i]; }
  if (t == 255) start[n] = excl;
}
__global__ void fill_csr_k(const int* __restrict__ erow, const int* __restrict__ start,
                           int* __restrict__ cur, int* __restrict__ eids) {
  int e = blockIdx.x * 256 + threadIdx.x;
  if (e >= N_EDGES) return;
  int r = erow[e];
  int p = atomicAdd(&cur[r], 1);
  eids[start[r] + p] = e;
}

// ---------------- generic bf16 MFMA GEMM: C(MxN) = act(A(MxK) @ B(NxK)^T + bias) ----------------
// MODE 0: A direct (stride K). MODE 1: A row m = X[idxr[m]] (stride 256, K==256).
// MODE 2: eu_in gather: K==1024; segs [x[row] | EBc[m] | EB[rev[m]] | x[col]], each 256 wide.
template<int MODE>
__global__ __launch_bounds__(256) void gemm_bf16(
    int M, int Nn, int K,
    const unsigned short* __restrict__ A,
    const unsigned short* __restrict__ X,
    const int* __restrict__ idxr, const int* __restrict__ idxc, const int* __restrict__ rev,
    const unsigned short* __restrict__ EB, const unsigned short* __restrict__ EBc,
    const unsigned short* __restrict__ ZP,
    const unsigned short* __restrict__ B,
    const float* __restrict__ bias,
    float* __restrict__ outF, int actF,
    unsigned short* __restrict__ outB, int actB)
{
  __shared__ __attribute__((aligned(16))) unsigned short As[128 * 64];
  __shared__ __attribute__((aligned(16))) unsigned short Bs[128 * 64];
  const int tid = threadIdx.x;
  const int bm = blockIdx.x, bn = blockIdx.y;
  const int lane = tid & 63, wid = tid >> 6;
  const int wm = wid >> 1, wn = wid & 1;
  const int l16 = lane & 15, quad = lane >> 4;

  const unsigned short* a0[4]; const unsigned short* a1p[4];
  const unsigned short* a2[4]; const unsigned short* a3[4];
  const unsigned short* brow[4];
  int gA[4];
  #pragma unroll
  for (int it = 0; it < 4; ++it) {
    int s = tid + it * 256;
    int r = s >> 3, gs = s & 7;
    gA[it] = gs ^ (r & 7);
    int mrow = bm * 128 + r; if (mrow >= M) mrow = M - 1;
    if constexpr (MODE == 0) {
      a0[it] = A + (size_t)mrow * K;
    } else if constexpr (MODE == 1) {
      a0[it] = X + (size_t)idxr[mrow] * 256;
    } else {
      a0[it]  = X + (size_t)idxr[mrow] * 256;
      a1p[it] = EBc + (size_t)mrow * 256;
      int rv = rev[mrow];
      a2[it]  = (rv < 0) ? ZP : (EB + (size_t)rv * 256);
      a3[it]  = X + (size_t)idxc[mrow] * 256;
    }
    brow[it] = B + (size_t)(bn * 128 + r) * K;
  }

  f32x4 acc[4][4];
  #pragma unroll
  for (int mi = 0; mi < 4; ++mi)
    #pragma unroll
    for (int ni = 0; ni < 4; ++ni)
      acc[mi][ni] = (f32x4){0.f, 0.f, 0.f, 0.f};

  const unsigned short* cur[4];
  #pragma unroll
  for (int it = 0; it < 4; ++it) cur[it] = a0[it];

  const int nkb = K >> 6;
  for (int kb = 0; kb < nkb; ++kb) {
    if constexpr (MODE == 2) {
      if ((kb & 3) == 0) {
        int seg = kb >> 2;
        #pragma unroll
        for (int it = 0; it < 4; ++it)
          cur[it] = (seg == 0) ? a0[it] : (seg == 1) ? a1p[it] : (seg == 2) ? a2[it] : a3[it];
      }
    }
    #pragma unroll
    for (int it = 0; it < 4; ++it) {
      int s = tid + it * 256;
      const unsigned short* src;
      if constexpr (MODE == 2) src = cur[it] + (kb & 3) * 64 + gA[it] * 8;
      else                     src = cur[it] + kb * 64 + gA[it] * 8;
      load_g2l16(src, &As[s * 8]);
    }
    #pragma unroll
    for (int it = 0; it < 4; ++it) {
      int s = tid + it * 256;
      load_g2l16(brow[it] + kb * 64 + gA[it] * 8, &Bs[s * 8]);
    }
    __syncthreads();
    #pragma unroll
    for (int ks = 0; ks < 2; ++ks) {
      bf16x8 af[4], bfv[4];
      #pragma unroll
      for (int mi = 0; mi < 4; ++mi) {
        int m = wm * 64 + mi * 16 + l16;
        int cell = (quad + ks * 4) ^ (m & 7);
        af[mi] = *(const bf16x8*)&As[m * 64 + cell * 8];
      }
      #pragma unroll
      for (int ni = 0; ni < 4; ++ni) {
        int n = wn * 64 + ni * 16 + l16;
        int cell = (quad + ks * 4) ^ (n & 7);
        bfv[ni] = *(const bf16x8*)&Bs[n * 64 + cell * 8];
      }
      #pragma unroll
      for (int mi = 0; mi < 4; ++mi)
        #pragma unroll
        for (int ni = 0; ni < 4; ++ni)
          acc[mi][ni] = __builtin_amdgcn_mfma_f32_16x16x32_bf16(af[mi], bfv[ni], acc[mi][ni], 0, 0, 0);
    }
    __syncthreads();
  }

  #pragma unroll
  for (int mi = 0; mi < 4; ++mi) {
    #pragma unroll
    for (int ni = 0; ni < 4; ++ni) {
      int gc = bn * 128 + wn * 64 + ni * 16 + l16;
      float bv = bias[gc];
      #pragma unroll
      for (int r = 0; r < 4; ++r) {
        int gr = bm * 128 + wm * 64 + mi * 16 + quad * 4 + r;
        if (gr < M) {
          float v = acc[mi][ni][r] + bv;
          if (outF) {
            float f = v;
            if (actF == 1) f = fmaxf(f, 0.f);
            else if (actF == 2) f = 1.f / (1.f + __expf(-f));
            outF[(size_t)gr * Nn + gc] = f;
          }
          if (outB) {
            float f = v;
            if (actB == 1) f = fmaxf(f, 0.f);
            outB[(size_t)gr * Nn + gc] = f2bf(f);
          }
        }
      }
    }
  }
}

// ---------------- attention: per-(edge,head) MLP + softmax + prob + weighted (NO atomics) ----------------
__global__ void attn_kernel(
    const unsigned short* __restrict__ q, const unsigned short* __restrict__ k,
    const unsigned short* __restrict__ v,
    const float* __restrict__ Wa1, const float* __restrict__ ba1,
    const float* __restrict__ Wa2, const float* __restrict__ ba2,
    float* __restrict__ prob_out, unsigned short* __restrict__ wout, int nE)
{
  __shared__ __attribute__((aligned(16))) float w1[64 * 64];
  __shared__ __attribute__((aligned(16))) float w2[32 * 64];
  __shared__ float b1s[64], b2s[32];
  for (int i = threadIdx.x; i < 4096; i += 256) w1[i] = Wa1[i];
  for (int i = threadIdx.x; i < 2048; i += 256) w2[i] = Wa2[i];
  if (threadIdx.x < 64) b1s[threadIdx.x] = ba1[threadIdx.x];
  else if (threadIdx.x < 96) b2s[threadIdx.x - 64] = ba2[threadIdx.x - 64];
  __syncthreads();
  int g = blockIdx.x * 256 + threadIdx.x;
  int e = g >> 3, h = g & 7;
  if (e >= nE) return;

  const unsigned short* qr = q + (size_t)e * 256 + h;
  const unsigned short* kr = k + (size_t)e * 256 + h;
  float xin[64];
  #pragma unroll
  for (int c = 0; c < 32; ++c) xin[c] = bf2f(qr[c * 8]);
  #pragma unroll
  for (int c = 0; c < 32; ++c) xin[32 + c] = bf2f(kr[c * 8]);

  float a1[64];
  #pragma unroll
  for (int o = 0; o < 64; ++o) {
    float s = b1s[o];
    #pragma unroll
    for (int c4 = 0; c4 < 16; ++c4) {
      float4 w = *(const float4*)&w1[o * 64 + c4 * 4];
      s += w.x * xin[c4 * 4] + w.y * xin[c4 * 4 + 1] + w.z * xin[c4 * 4 + 2] + w.w * xin[c4 * 4 + 3];
    }
    a1[o] = fmaxf(s, 0.f);
  }

  float att[32];
  float mx = -1e30f;
  #pragma unroll
  for (int o = 0; o < 32; ++o) {
    float s = b2s[o];
    #pragma unroll
    for (int c4 = 0; c4 < 16; ++c4) {
      float4 w = *(const float4*)&w2[o * 64 + c4 * 4];
      s += w.x * a1[c4 * 4] + w.y * a1[c4 * 4 + 1] + w.z * a1[c4 * 4 + 2] + w.w * a1[c4 * 4 + 3];
    }
    att[o] = s;
    mx = fmaxf(mx, s);
  }
  float denom = 0.f;
  #pragma unroll
  for (int o = 0; o < 32; ++o) { att[o] = __expf((att[o] - mx) * INV_TEMP); denom += att[o]; }
  float inv = 1.f / denom;

  const unsigned short* vr = v + (size_t)e * 256 + h;
  float* pr = prob_out + (size_t)e * 256 + h;
  unsigned short* wr = wout + (size_t)e * 256 + h;
  #pragma unroll
  for (int o = 0; o < 32; ++o) {
    float p = att[o] * inv;
    pr[o * 8] = p;
    wr[o * 8] = f2bf(p * bf2f(vr[o * 8]));
  }
}

// ---------------- zero-atomic segment max over out-edges (CSR gather) ----------------
__global__ void agg_gather_k(const unsigned short* __restrict__ w,
                             const int* __restrict__ ostart, const int* __restrict__ oeids,
                             float* __restrict__ agg) {
  int n = blockIdx.x, d = threadIdx.x;
  int s = ostart[n], t = ostart[n + 1];
  float m = -1e30f;
  for (int i = s; i < t; ++i) {
    int e = oeids[i];
    m = fmaxf(m, bf2f(w[(size_t)e * 256 + d]));
  }
  agg[(size_t)n * 256 + d] = (s < t) ? m : 0.f;
}

// ---------------- scatter reductions / small fusions ----------------
__global__ void edge_sums_k(const unsigned short* __restrict__ ueb, const int* __restrict__ ei,
                            float* __restrict__ osum, float* __restrict__ isum) {
  int e = blockIdx.x, d = threadIdx.x;
  float v = bf2f(ueb[(size_t)e * 256 + d]);
  atomicAdd(&osum[(size_t)ei[e] * 256 + d], v);
  atomicAdd(&isum[(size_t)ei[N_EDGES + e] * 256 + d], v);
}
__global__ void build_node_in_k(const unsigned short* __restrict__ xb, const float* __restrict__ agg,
                                unsigned short* __restrict__ node_in) {
  int n = blockIdx.x, d = threadIdx.x;
  node_in[(size_t)n * 512 + d] = xb[(size_t)n * 256 + d];
  float a = agg[(size_t)n * 256 + d];
  unsigned int u = __float_as_uint(a);
  if ((u & 0x7f800000u) == 0x7f800000u) a = 0.f;  // inf/nan guard
  node_in[(size_t)n * 512 + 256 + d] = f2bf(a);
}
__global__ void build_twin_k(const float* __restrict__ osum, const float* __restrict__ isum,
                             const int* __restrict__ ocnt, const int* __restrict__ icnt,
                             unsigned short* __restrict__ twin) {
  int n = blockIdx.x, d = threadIdx.x;
  float oc = (float)(ocnt[n] > 1 ? ocnt[n] : 1);
  float ic = (float)(icnt[n] > 1 ? icnt[n] : 1);
  twin[(size_t)n * 512 + d]       = f2bf(osum[(size_t)n * 256 + d] / oc);
  twin[(size_t)n * 512 + 256 + d] = f2bf(isum[(size_t)n * 256 + d] / ic);
}
__global__ void final_node_k(const float* __restrict__ un, const float* __restrict__ eatt,
                             float* __restrict__ outp) {
  size_t g = (size_t)blockIdx.x * 256 + threadIdx.x;
  float v = fmaxf(un[g], 0.f) * eatt[g];
  outp[g] = fmaxf(v, 0.f);
}

// ---------------- host driver ----------------
struct GP {
  int M, Nn, K;
  const unsigned short *A, *X; const int *idxr, *idxc, *rev;
  const unsigned short *EB, *EBc, *ZP, *B; const float* bias;
  float* outF; int actF; unsigned short* outB; int actB;
};
static void launch_gemm(int mode, const GP& p, hipStream_t s) {
  dim3 g((unsigned)((p.M + 127) / 128), (unsigned)(p.Nn / 128)), b(256);
  if (mode == 0)
    gemm_bf16<0><<<g, b, 0, s>>>(p.M, p.Nn, p.K, p.A, p.X, p.idxr, p.idxc, p.rev, p.EB, p.EBc, p.ZP, p.B, p.bias, p.outF, p.actF, p.outB, p.actB);
  else if (mode == 1)
    gemm_bf16<1><<<g, b, 0, s>>>(p.M, p.Nn, p.K, p.A, p.X, p.idxr, p.idxc, p.rev, p.EB, p.EBc, p.ZP, p.B, p.bias, p.outF, p.actF, p.outB, p.actB);
  else
    gemm_bf16<2><<<g, b, 0, s>>>(p.M, p.Nn, p.K, p.A, p.X, p.idxr, p.idxc, p.rev, p.EB, p.EBc, p.ZP, p.B, p.bias, p.outF, p.actF, p.outB, p.actB);
}

extern "C" void kernel_launch(void* const* d_in, const int* in_sizes, int n_in,
                              void* d_out, int out_size, void* d_ws, size_t ws_size,
                              hipStream_t stream) {
  (void)in_sizes; (void)n_in; (void)out_size;
  const float* x   = (const float*)d_in[0];
  const float* ea  = (const float*)d_in[1];
  const float* Wq  = (const float*)d_in[2];  const float* bq  = (const float*)d_in[3];
  const float* Wk  = (const float*)d_in[4];  const float* bk  = (const float*)d_in[5];
  const float* Wv  = (const float*)d_in[6];  const float* bv  = (const float*)d_in[7];
  const float* We1 = (const float*)d_in[8];  const float* be1 = (const float*)d_in[9];
  const float* We2 = (const float*)d_in[10]; const float* be2 = (const float*)d_in[11];
  const float* Wea = (const float*)d_in[12]; const float* bea = (const float*)d_in[13];
  const float* Wn1 = (const float*)d_in[14]; const float* bn1 = (const float*)d_in[15];
  const float* Wn2 = (const float*)d_in[16]; const float* bn2 = (const float*)d_in[17];
  const float* Wa1 = (const float*)d_in[18]; const float* ba1 = (const float*)d_in[19];
  const float* Wa2 = (const float*)d_in[20]; const float* ba2 = (const float*)d_in[21];
  const int*   ei  = (const int*)d_in[22];

  float* out_nf = (float*)d_out;
  float* out_ef = out_nf + (size_t)N_NODES * 256;
  float* out_pr = out_ef + (size_t)N_EDGES * 256;

  uint8_t* base = (uint8_t*)d_ws;
  size_t off = 0;
  auto alloc = [&](size_t bytes) -> void* {
    void* r = base + off; off += (bytes + 255) & ~(size_t)255; return r;
  };

  // zero-initialized region
  size_t zero_start = off;
  float* osum = (float*)alloc((size_t)N_NODES * 256 * 4);
  float* isum = (float*)alloc((size_t)N_NODES * 256 * 4);
  int*   ocnt = (int*)alloc((size_t)N_NODES * 4);
  int*   icnt = (int*)alloc((size_t)N_NODES * 4);
  int*   ocur = (int*)alloc((size_t)N_NODES * 4);
  unsigned short* zp = (unsigned short*)alloc(512);
  size_t zero_bytes = off - zero_start;
  // 0xFF-initialized region (hash = empty)
  size_t ff_start = off;
  unsigned long long* htab = (unsigned long long*)alloc((size_t)HSIZE * 8);
  size_t ff_bytes = off - ff_start;

  float* agg = (float*)alloc((size_t)N_NODES * 256 * 4);
  int* ostart = (int*)alloc((size_t)(N_NODES + 1) * 4);
  int* oeids  = (int*)alloc((size_t)N_EDGES * 4);

  unsigned short* xb   = (unsigned short*)alloc((size_t)N_NODES * 256 * 2);
  unsigned short* eb   = (unsigned short*)alloc((size_t)N_EDGES * 256 * 2);
  unsigned short* ueb  = (unsigned short*)alloc((size_t)N_EDGES * 256 * 2);
  unsigned short* Wqb  = (unsigned short*)alloc(65536 * 2);
  unsigned short* Wkb  = (unsigned short*)alloc(65536 * 2);
  unsigned short* Wvb  = (unsigned short*)alloc(65536 * 2);
  unsigned short* We1b = (unsigned short*)alloc(786432 * 2);
  unsigned short* We2b = (unsigned short*)alloc(196608 * 2);
  unsigned short* Wn1b = (unsigned short*)alloc(262144 * 2);
  unsigned short* Wn2b = (unsigned short*)alloc(131072 * 2);
  unsigned short* Weab = (unsigned short*)alloc(131072 * 2);
  int* rev = (int*)alloc((size_t)N_EDGES * 4);
  unsigned short* node_in = (unsigned short*)alloc((size_t)N_NODES * 512 * 2);
  unsigned short* twinb   = (unsigned short*)alloc((size_t)N_NODES * 512 * 2);
  unsigned short* hnb     = (unsigned short*)alloc((size_t)N_NODES * 512 * 2);
  float* un   = (float*)alloc((size_t)N_NODES * 256 * 4);
  float* eatt = (float*)alloc((size_t)N_NODES * 256 * 4);

  // shared chunk region: phase A uses q/k/v (3*512 B per edge), phase B uses h (1536 B per edge)
  size_t remain = (ws_size > off) ? ws_size - off : 0;
  long long ecap = (long long)(remain / 1536);
  int Ec = (ecap < (long long)N_EDGES) ? (int)ecap : N_EDGES;
  Ec = (Ec / 128) * 128; if (Ec < 128) Ec = 128;
  unsigned short* chunkbuf = (unsigned short*)(base + off);

  hipMemsetAsync(base + zero_start, 0, zero_bytes, stream);
  hipMemsetAsync(base + ff_start, 0xFF, ff_bytes, stream);

  auto cast = [&](const float* s, unsigned short* dd, size_t n) {
    cast_bf16_k<<<dim3((unsigned)((n / 4 + 255) / 256)), dim3(256), 0, stream>>>(s, dd, (int)n);
  };
  cast(x,  xb, (size_t)N_NODES * 256);
  cast(ea, eb, (size_t)N_EDGES * 256);
  cast(Wq, Wqb, 65536);   cast(Wk, Wkb, 65536);   cast(Wv, Wvb, 65536);
  cast(We1, We1b, 786432); cast(We2, We2b, 196608);
  cast(Wn1, Wn1b, 262144); cast(Wn2, Wn2b, 131072); cast(Wea, Weab, 131072);

  hash_insert_k<<<(N_EDGES + 255) / 256, 256, 0, stream>>>(ei, htab);
  hash_lookup_k<<<(N_EDGES + 255) / 256, 256, 0, stream>>>(ei, htab, rev);

  // ---- CSR (row) build: degree -> scan -> fill ----
  degree_k<<<(N_EDGES + 255) / 256, 256, 0, stream>>>(ei, ocnt, icnt);
  scan_k<<<1, 256, 0, stream>>>(ocnt, ostart, N_NODES);
  fill_csr_k<<<(N_EDGES + 255) / 256, 256, 0, stream>>>(ei, ostart, ocur, oeids);

  // ---- attention phase (q/k/v projections + fused attention), chunked ----
  // weighted = prob*v is written (bf16) into ueb, which is dead until edge-update phase.
  unsigned short* qc = chunkbuf;
  unsigned short* kc = qc + (size_t)Ec * 256;
  unsigned short* vc = kc + (size_t)Ec * 256;
  for (int e0 = 0; e0 < N_EDGES; e0 += Ec) {
    int n = (N_EDGES - e0 < Ec) ? (N_EDGES - e0) : Ec;
    GP p{};
    p.M = n; p.Nn = 256; p.K = 256; p.ZP = zp;
    p.X = xb; p.idxr = ei + e0; p.B = Wqb; p.bias = bq; p.outB = qc;
    launch_gemm(1, p, stream);
    p.X = nullptr; p.idxr = nullptr; p.A = eb + (size_t)e0 * 256; p.B = Wkb; p.bias = bk; p.outB = kc;
    launch_gemm(0, p, stream);
    p.A = nullptr; p.X = xb; p.idxr = ei + N_EDGES + e0; p.B = Wvb; p.bias = bv; p.outB = vc;
    launch_gemm(1, p, stream);
    attn_kernel<<<dim3((unsigned)((n * 8 + 255) / 256)), dim3(256), 0, stream>>>(
        qc, kc, vc, Wa1, ba1, Wa2, ba2, out_pr + (size_t)e0 * 256, ueb + (size_t)e0 * 256, n);
  }

  // ---- zero-atomic segment max (reads weighted from ueb before it's overwritten) ----
  agg_gather_k<<<dim3(N_NODES), dim3(256), 0, stream>>>(ueb, ostart, oeids, agg);
  build_node_in_k<<<dim3(N_NODES), dim3(256), 0, stream>>>(xb, agg, node_in);

  // ---- edge-update MLP, chunked (reuses chunk region for h; overwrites ueb) ----
  unsigned short* hc = chunkbuf;
  for (int e0 = 0; e0 < N_EDGES; e0 += Ec) {
    int n = (N_EDGES - e0 < Ec) ? (N_EDGES - e0) : Ec;
    GP p{};
    p.M = n; p.Nn = 768; p.K = 1024;
    p.X = xb; p.idxr = ei + e0; p.idxc = ei + N_EDGES + e0; p.rev = rev + e0;
    p.EB = eb; p.EBc = eb + (size_t)e0 * 256; p.ZP = zp;
    p.B = We1b; p.bias = be1; p.outB = hc; p.actB = 1;
    launch_gemm(2, p, stream);
    GP p2{};
    p2.M = n; p2.Nn = 256; p2.K = 768; p2.ZP = zp;
    p2.A = hc; p2.B = We2b; p2.bias = be2;
    p2.outF = out_ef + (size_t)e0 * 256; p2.actF = 1;   // relu -> edge_feature output
    p2.outB = ueb + (size_t)e0 * 256;    p2.actB = 0;   // raw  -> for segment sums
    launch_gemm(0, p2, stream);
  }

  edge_sums_k<<<dim3(N_EDGES), dim3(256), 0, stream>>>(ueb, ei, osum, isum);
  build_twin_k<<<dim3(N_NODES), dim3(256), 0, stream>>>(osum, isum, ocnt, icnt, twinb);

  GP pn{};
  pn.M = N_NODES; pn.Nn = 512; pn.K = 512; pn.ZP = zp;
  pn.A = node_in; pn.B = Wn1b; pn.bias = bn1; pn.outB = hnb; pn.actB = 1;
  launch_gemm(0, pn, stream);
  GP pn2{};
  pn2.M = N_NODES; pn2.Nn = 256; pn2.K = 512; pn2.ZP = zp;
  pn2.A = hnb; pn2.B = Wn2b; pn2.bias = bn2; pn2.outF = un; pn2.actF = 0;
  launch_gemm(0, pn2, stream);
  GP pe{};
  pe.M = N_NODES; pe.Nn = 256; pe.K = 512; pe.ZP = zp;
  pe.A = twinb; pe.B = Weab; pe.bias = bea; pe.outF = eatt; pe.actF = 2;  // sigmoid
  launch_gemm(0, pe, stream);

  final_node_k<<<dim3(N_NODES), dim3(256), 0, stream>>>(un, eatt, out_nf);
}